// Round 1
// baseline (1259.172 us; speedup 1.0000x reference)
//
#include <hip/hip_runtime.h>

#define NL 8
#define NM 8192
#define ND 16
#define NH 256
#define NF 64
#define NN (NL * NM)

__device__ __forceinline__ float lrelu(float x) { return fmaxf(x, 0.1f * x); }

// ---------------- Level 0: h = mlp_pi(delay)  (M,1)->(M,128)->(M,256) ----------------
__global__ __launch_bounds__(256) void level0_kernel(
    const float* __restrict__ delay,
    const float* __restrict__ W1, const float* __restrict__ b1,
    const float* __restrict__ W2, const float* __restrict__ b2,
    float* __restrict__ h_all)
{
    const int tid = threadIdx.x;
    const int row0 = blockIdx.x * 16;
    __shared__ float shid[16][128];
    __shared__ float sdel[16];
    if (tid < 16) sdel[tid] = delay[row0 + tid];
    __syncthreads();
    for (int x = tid; x < 16 * 128; x += 256) {
        int r = x >> 7, j = x & 127;
        shid[r][j] = lrelu(sdel[r] * W1[j] + b1[j]);
    }
    __syncthreads();
    for (int x = tid; x < 16 * 256; x += 256) {
        int r = x >> 8, k = x & 255;
        float acc = b2[k];
        #pragma unroll 8
        for (int j = 0; j < 128; ++j) acc += shid[r][j] * W2[j * 256 + k];
        h_all[(row0 + r) * 256 + k] = acc;
    }
}

// ---------------- Attention per level: computes neigh (M,256) ----------------
__global__ __launch_bounds__(256) void attn_kernel(
    const float* __restrict__ h_all, const float* __restrict__ feat,
    const float* __restrict__ bit_pos, const int* __restrict__ nbr_idx,
    const float* __restrict__ W_t1, const float* __restrict__ b_t1,
    const float* __restrict__ W_t2, const float* __restrict__ b_t2,
    const float* __restrict__ W_p1, const float* __restrict__ b_p1,
    const float* __restrict__ W_p2, const float* __restrict__ b_p2,
    const float* __restrict__ av,
    float* __restrict__ neigh, int level)
{
    const int m = blockIdx.x;
    const int tid = threadIdx.x;
    __shared__ float sh[16][256];   // gathered h_src
    __shared__ float s_e[16];
    __shared__ float s_p1[16][32];
    __shared__ float s_t1[32];
    __shared__ float s_et;
    __shared__ int   s_idx[16];

    if (tid < 16) s_idx[tid] = nbr_idx[((level - 1) * NM + m) * ND + tid];
    __syncthreads();

    // gather 16 x 256 rows of h_all
    for (int x = tid; x < 16 * 256; x += 256) {
        int d = x >> 8, k = x & 255;
        sh[d][k] = h_all[s_idx[d] * 256 + k];
    }
    __syncthreads();

    // e_t: scalar mlp_t(feat_row) . av_t  (threads 0..31)
    if (tid < 32) {
        const float* frow = feat + (size_t)(level * NM + m) * NF;
        float acc = b_t1[tid];
        #pragma unroll 8
        for (int f = 0; f < 64; ++f) acc += frow[f] * W_t1[f * 32 + tid];
        s_t1[tid] = lrelu(acc);
    }
    __syncthreads();
    if (tid < 32) {
        float acc = b_t2[tid];
        #pragma unroll 8
        for (int q = 0; q < 32; ++q) acc += s_t1[q] * W_t2[q * 32 + tid];
        float part = acc * av[tid];
        for (int off = 16; off; off >>= 1) part += __shfl_down(part, off);
        if (tid == 0) s_et = part;
    }

    // e_p: per-d mlp_p(bit_pos scalar); group g=tid>>4 handles neighbor d=g
    const int g = tid >> 4, l = tid & 15;
    const float xbp = bit_pos[((size_t)(level - 1) * NM + m) * ND + g];
    {
        int j0 = l, j1 = l + 16;
        s_p1[g][j0] = lrelu(xbp * W_p1[j0] + b_p1[j0]);
        s_p1[g][j1] = lrelu(xbp * W_p1[j1] + b_p1[j1]);
    }
    __syncthreads();
    {
        float part = 0.f;
        #pragma unroll
        for (int jj = 0; jj < 2; ++jj) {
            int j = l + jj * 16;
            float acc = b_p2[j];
            #pragma unroll 8
            for (int q = 0; q < 32; ++q) acc += s_p1[g][q] * W_p2[q * 32 + j];
            part += acc * av[32 + j];
        }
        // e_h: dot(h_src[g], av_h)
        for (int k = l; k < 256; k += 16) part += sh[g][k] * av[64 + k];
        for (int off = 8; off; off >>= 1) part += __shfl_xor(part, off);
        if (l == 0) s_e[g] = part;   // s_et added below after sync
    }
    __syncthreads();

    // softmax over 16 + weighted sum; thread k handles output dim k
    {
        float et = s_et;
        float mx = -1e30f;
        #pragma unroll
        for (int d = 0; d < 16; ++d) mx = fmaxf(mx, s_e[d] + et);
        float denom = 0.f;
        float w[16];
        #pragma unroll
        for (int d = 0; d < 16; ++d) { w[d] = expf(s_e[d] + et - mx); denom += w[d]; }
        float inv = 1.f / denom;
        float acc = 0.f;
        #pragma unroll
        for (int d = 0; d < 16; ++d) acc += w[d] * sh[d][tid];
        neigh[(size_t)m * 256 + tid] = acc * inv;
    }
}

// ---------------- Neighborhood MLP per level: h = relu?(mlp_n(neigh)) ----------------
__global__ __launch_bounds__(256) void mlp_n_kernel(
    const float* __restrict__ neigh,
    const float* __restrict__ W1, const float* __restrict__ b1,
    const float* __restrict__ W2, const float* __restrict__ b2,
    const int* __restrict__ is_po,
    float* __restrict__ h_all, int level)
{
    const int tid = threadIdx.x;
    const int row0 = blockIdx.x * 16;
    __shared__ float sn[16][256];
    __shared__ float shid[16][128];
    for (int x = tid; x < 16 * 256; x += 256) {
        int r = x >> 8, k = x & 255;
        sn[r][k] = neigh[(size_t)(row0 + r) * 256 + k];
    }
    __syncthreads();
    for (int x = tid; x < 16 * 128; x += 256) {
        int r = x >> 7, j = x & 127;
        float acc = b1[j];
        #pragma unroll 8
        for (int k = 0; k < 256; ++k) acc += sn[r][k] * W1[k * 128 + j];
        shid[r][j] = lrelu(acc);
    }
    __syncthreads();
    for (int x = tid; x < 16 * 256; x += 256) {
        int r = x >> 8, k = x & 255;
        float acc = b2[k];
        #pragma unroll 8
        for (int j = 0; j < 128; ++j) acc += shid[r][j] * W2[j * 256 + k];
        int gm = level * NM + row0 + r;
        if (is_po[gm] != 1) acc = fmaxf(acc, 0.f);
        h_all[(size_t)gm * 256 + k] = acc;
    }
}

// ---------------- Final: out = mlp_o(concat(h_gnn, mlp_g(po_feat))) ----------------
__global__ __launch_bounds__(256) void final_kernel(
    const float* __restrict__ h_gnn, const float* __restrict__ po_feat,
    const float* __restrict__ W_g1, const float* __restrict__ b_g1,
    const float* __restrict__ W_g2, const float* __restrict__ b_g2,
    const float* __restrict__ W_o1, const float* __restrict__ b_o1,
    const float* __restrict__ W_o2, const float* __restrict__ b_o2,
    float* __restrict__ out)
{
    const int tid = threadIdx.x;
    const int row0 = blockIdx.x * 16;
    __shared__ float sx[16][512];
    __shared__ float sg1[16][128];
    __shared__ float so1[16][256];
    __shared__ float spo[16];
    if (tid < 16) spo[tid] = po_feat[row0 + tid];
    for (int x = tid; x < 16 * 256; x += 256) {
        int r = x >> 8, k = x & 255;
        sx[r][k] = h_gnn[(size_t)(row0 + r) * 256 + k];
    }
    __syncthreads();
    for (int x = tid; x < 16 * 128; x += 256) {
        int r = x >> 7, j = x & 127;
        sg1[r][j] = lrelu(spo[r] * W_g1[j] + b_g1[j]);
    }
    __syncthreads();
    for (int x = tid; x < 16 * 256; x += 256) {
        int r = x >> 8, k = x & 255;
        float acc = b_g2[k];
        #pragma unroll 8
        for (int j = 0; j < 128; ++j) acc += sg1[r][j] * W_g2[j * 256 + k];
        sx[r][256 + k] = acc;
    }
    __syncthreads();
    for (int x = tid; x < 16 * 256; x += 256) {
        int r = x >> 8, k = x & 255;
        float acc = b_o1[k];
        #pragma unroll 8
        for (int j = 0; j < 512; ++j) acc += sx[r][j] * W_o1[j * 256 + k];
        so1[r][k] = lrelu(acc);
    }
    __syncthreads();
    {
        int g = tid >> 4, l = tid & 15;
        float acc = 0.f;
        for (int k = l; k < 256; k += 16) acc += so1[g][k] * W_o2[k];
        for (int off = 8; off; off >>= 1) acc += __shfl_xor(acc, off);
        if (l == 0) out[row0 + g] = acc + b_o2[0];
    }
}

extern "C" void kernel_launch(void* const* d_in, const int* in_sizes, int n_in,
                              void* d_out, int out_size, void* d_ws, size_t ws_size,
                              hipStream_t stream) {
    const float* W_pi1 = (const float*)d_in[0];
    const float* b_pi1 = (const float*)d_in[1];
    const float* W_pi2 = (const float*)d_in[2];
    const float* b_pi2 = (const float*)d_in[3];
    const float* W_t1  = (const float*)d_in[4];
    const float* b_t1  = (const float*)d_in[5];
    const float* W_t2  = (const float*)d_in[6];
    const float* b_t2  = (const float*)d_in[7];
    const float* W_p1  = (const float*)d_in[8];
    const float* b_p1  = (const float*)d_in[9];
    const float* W_p2  = (const float*)d_in[10];
    const float* b_p2  = (const float*)d_in[11];
    const float* W_n1  = (const float*)d_in[12];
    const float* b_n1  = (const float*)d_in[13];
    const float* W_n2  = (const float*)d_in[14];
    const float* b_n2  = (const float*)d_in[15];
    const float* W_g1  = (const float*)d_in[16];
    const float* b_g1  = (const float*)d_in[17];
    const float* W_g2  = (const float*)d_in[18];
    const float* b_g2  = (const float*)d_in[19];
    const float* W_o1  = (const float*)d_in[20];
    const float* b_o1  = (const float*)d_in[21];
    const float* W_o2  = (const float*)d_in[22];
    const float* b_o2  = (const float*)d_in[23];
    const float* av    = (const float*)d_in[24];
    const float* feat  = (const float*)d_in[25];
    const float* delay = (const float*)d_in[26];
    const float* bit_pos = (const float*)d_in[27];
    const float* po_feat = (const float*)d_in[28];
    const int*   is_po   = (const int*)d_in[29];
    const int*   nbr_idx = (const int*)d_in[30];

    float* h_all = (float*)d_ws;                       // NN * 256 floats
    float* neigh = h_all + (size_t)NN * 256;           // NM * 256 floats
    float* out   = (float*)d_out;

    dim3 blk(256);

    level0_kernel<<<NM / 16, blk, 0, stream>>>(delay, W_pi1, b_pi1, W_pi2, b_pi2, h_all);

    for (int level = 1; level < NL; ++level) {
        attn_kernel<<<NM, blk, 0, stream>>>(h_all, feat, bit_pos, nbr_idx,
                                            W_t1, b_t1, W_t2, b_t2,
                                            W_p1, b_p1, W_p2, b_p2,
                                            av, neigh, level);
        mlp_n_kernel<<<NM / 16, blk, 0, stream>>>(neigh, W_n1, b_n1, W_n2, b_n2,
                                                  is_po, h_all, level);
    }

    final_kernel<<<NM / 16, blk, 0, stream>>>(h_all + (size_t)(NN - NM) * 256, po_feat,
                                              W_g1, b_g1, W_g2, b_g2,
                                              W_o1, b_o1, W_o2, b_o2, out);
}

// Round 2
// 643.882 us; speedup vs baseline: 1.9556x; 1.9556x over previous
//
#include <hip/hip_runtime.h>

#define NL 8
#define NM 8192
#define ND 16
#define NH 256
#define NF 64
#define NN (NL * NM)

__device__ __forceinline__ float lrelu(float x) { return fmaxf(x, 0.1f * x); }

// ---------- precompute attention constants: cst[0..31]=W_t2@av_t, [32..63]=W_p2@av_p, [64]=b_t2.av_t, [65]=b_p2.av_p
__global__ void precomp_kernel(const float* __restrict__ W_t2, const float* __restrict__ b_t2,
                               const float* __restrict__ W_p2, const float* __restrict__ b_p2,
                               const float* __restrict__ av, float* __restrict__ cst)
{
    int t = threadIdx.x;
    if (t < 32) {
        float w = 0.f;
        for (int q = 0; q < 32; ++q) w += W_t2[t * 32 + q] * av[q];
        cst[t] = w;
    } else {
        int j = t - 32;
        float w = 0.f;
        for (int k = 0; k < 32; ++k) w += W_p2[j * 32 + k] * av[32 + k];
        cst[32 + j] = w;
    }
    if (t == 0)  { float s = 0.f; for (int q = 0; q < 32; ++q) s += b_t2[q] * av[q];      cst[64] = s; }
    if (t == 33) { float s = 0.f; for (int k = 0; k < 32; ++k) s += b_p2[k] * av[32 + k]; cst[65] = s; }
}

// ---------- Level 0: h = mlp_pi(delay), 512 thr / 32 rows ----------
__global__ __launch_bounds__(512) void level0_kernel(
    const float* __restrict__ delay,
    const float* __restrict__ W1, const float* __restrict__ b1,
    const float* __restrict__ W2, const float* __restrict__ b2,
    float* __restrict__ h_all)
{
    const int tid = threadIdx.x;
    const int row0 = blockIdx.x * 32;
    __shared__ __align__(16) float sH[32][128];

    for (int x = tid; x < 32 * 128; x += 512) {
        int r = x >> 7, j = x & 127;
        sH[r][j] = lrelu(delay[row0 + r] * W1[j] + b1[j]);
    }
    __syncthreads();

    // layer2: (32x128)@(128x256)
    const int tj = tid & 63, tr = tid >> 6;   // j0=tj*4, rows tr*4..tr*4+3
    float acc[4][4];
    #pragma unroll
    for (int a = 0; a < 4; ++a)
        #pragma unroll
        for (int b = 0; b < 4; ++b) acc[a][b] = 0.f;

    for (int k = 0; k < 128; k += 4) {
        float4 w0 = *(const float4*)(W2 + (size_t)(k + 0) * 256 + tj * 4);
        float4 w1 = *(const float4*)(W2 + (size_t)(k + 1) * 256 + tj * 4);
        float4 w2 = *(const float4*)(W2 + (size_t)(k + 2) * 256 + tj * 4);
        float4 w3 = *(const float4*)(W2 + (size_t)(k + 3) * 256 + tj * 4);
        #pragma unroll
        for (int rr = 0; rr < 4; ++rr) {
            float4 xv = *(const float4*)(&sH[tr * 4 + rr][k]);
            acc[rr][0] += xv.x * w0.x + xv.y * w1.x + xv.z * w2.x + xv.w * w3.x;
            acc[rr][1] += xv.x * w0.y + xv.y * w1.y + xv.z * w2.y + xv.w * w3.y;
            acc[rr][2] += xv.x * w0.z + xv.y * w1.z + xv.z * w2.z + xv.w * w3.z;
            acc[rr][3] += xv.x * w0.w + xv.y * w1.w + xv.z * w2.w + xv.w * w3.w;
        }
    }
    float4 bv = *(const float4*)(b2 + tj * 4);
    #pragma unroll
    for (int rr = 0; rr < 4; ++rr) {
        float4 o;
        o.x = acc[rr][0] + bv.x; o.y = acc[rr][1] + bv.y;
        o.z = acc[rr][2] + bv.z; o.w = acc[rr][3] + bv.w;
        *(float4*)(h_all + (size_t)(row0 + tr * 4 + rr) * NH + tj * 4) = o;
    }
}

// ---------- Attention per level: one wave per m, zero LDS ----------
__global__ __launch_bounds__(256) void attn_kernel(
    const float* __restrict__ h_all, const float* __restrict__ feat,
    const float* __restrict__ bit_pos, const int* __restrict__ nbr_idx,
    const float* __restrict__ W_t1, const float* __restrict__ b_t1,
    const float* __restrict__ W_p1, const float* __restrict__ b_p1,
    const float* __restrict__ av, const float* __restrict__ cst,
    float* __restrict__ neigh, int level)
{
    const int m = (blockIdx.x * 256 + threadIdx.x) >> 6;
    const int lane = threadIdx.x & 63;

    int idx_l = 0;
    if (lane < ND) idx_l = nbr_idx[((size_t)(level - 1) * NM + m) * ND + lane];

    // e_h[d] = h_src[d] . av_h   (lane = d*4 + q, q = quarter of 256)
    const int d = lane >> 2, q = lane & 3;
    const int row = __shfl(idx_l, d);
    const float* hp = h_all + (size_t)row * NH + q * 64;
    const float* ap = av + 64 + q * 64;
    float eh = 0.f;
    #pragma unroll
    for (int t = 0; t < 16; ++t) {
        float4 hv = *(const float4*)(hp + t * 4);
        float4 avv = *(const float4*)(ap + t * 4);
        eh += hv.x * avv.x + hv.y * avv.y + hv.z * avv.z + hv.w * avv.w;
    }
    eh += __shfl_xor(eh, 1);
    eh += __shfl_xor(eh, 2);

    // e_p[d]: collapsed mlp_p (lanes 0..15)
    float ep = 0.f;
    if (lane < ND) {
        float x = bit_pos[((size_t)(level - 1) * NM + m) * ND + lane];
        #pragma unroll 8
        for (int j = 0; j < 32; ++j)
            ep += cst[32 + j] * lrelu(x * W_p1[j] + b_p1[j]);
        ep += cst[65];
    }

    // e_t: collapsed mlp_t (lanes 0..31)
    float et = 0.f;
    if (lane < 32) {
        const float* frow = feat + (size_t)(level * NM + m) * NF;
        float acc = b_t1[lane];
        #pragma unroll 8
        for (int f = 0; f < NF; ++f) acc += frow[f] * W_t1[f * 32 + lane];
        et = lrelu(acc) * cst[lane];
    }
    #pragma unroll
    for (int off = 1; off < 32; off <<= 1) et += __shfl_xor(et, off);
    const float etb = __shfl(et, 0) + cst[64];

    // combine + softmax over d within each 16-lane group
    const int dd = lane & 15;
    float e = __shfl(eh, dd * 4) + __shfl(ep, dd) + etb;
    float mx = e;
    #pragma unroll
    for (int off = 1; off < 16; off <<= 1) mx = fmaxf(mx, __shfl_xor(mx, off));
    float w = __expf(e - mx);
    float s = w;
    #pragma unroll
    for (int off = 1; off < 16; off <<= 1) s += __shfl_xor(s, off);
    const float alpha = w / s;

    // neigh[m] = sum_d alpha_d * h_src[d]; lane owns cols lane*4..lane*4+3
    float4 acc4 = make_float4(0.f, 0.f, 0.f, 0.f);
    #pragma unroll
    for (int dn = 0; dn < ND; ++dn) {
        float a = __shfl(alpha, dn);
        int r = __shfl(idx_l, dn);
        float4 v = *(const float4*)(h_all + (size_t)r * NH + lane * 4);
        acc4.x += a * v.x; acc4.y += a * v.y; acc4.z += a * v.z; acc4.w += a * v.w;
    }
    *(float4*)(neigh + (size_t)m * NH + lane * 4) = acc4;
}

// ---------- Neighborhood MLP per level: 512 thr / 32 rows ----------
__global__ __launch_bounds__(512) void mlp_n_kernel(
    const float* __restrict__ neigh,
    const float* __restrict__ W1, const float* __restrict__ b1,
    const float* __restrict__ W2, const float* __restrict__ b2,
    const int* __restrict__ is_po,
    float* __restrict__ h_all, int level)
{
    const int tid = threadIdx.x;
    const int row0 = blockIdx.x * 32;
    __shared__ __align__(16) float sX[32][NH];
    __shared__ __align__(16) float sH[32][128];

    for (int x = tid; x < 32 * 64; x += 512) {
        int r = x >> 6, c = x & 63;
        *(float4*)(&sX[r][c * 4]) = *(const float4*)(neigh + (size_t)(row0 + r) * NH + c * 4);
    }
    __syncthreads();

    // layer 1: (32x256)@(256x128), lrelu
    {
        const int tj = tid & 31, tr = tid >> 5;   // j0=tj*4, rows tr*2..tr*2+1
        float acc[2][4];
        #pragma unroll
        for (int a = 0; a < 2; ++a)
            #pragma unroll
            for (int b = 0; b < 4; ++b) acc[a][b] = 0.f;

        for (int k = 0; k < NH; k += 4) {
            float4 w0 = *(const float4*)(W1 + (size_t)(k + 0) * 128 + tj * 4);
            float4 w1 = *(const float4*)(W1 + (size_t)(k + 1) * 128 + tj * 4);
            float4 w2 = *(const float4*)(W1 + (size_t)(k + 2) * 128 + tj * 4);
            float4 w3 = *(const float4*)(W1 + (size_t)(k + 3) * 128 + tj * 4);
            #pragma unroll
            for (int rr = 0; rr < 2; ++rr) {
                float4 xv = *(const float4*)(&sX[tr * 2 + rr][k]);
                acc[rr][0] += xv.x * w0.x + xv.y * w1.x + xv.z * w2.x + xv.w * w3.x;
                acc[rr][1] += xv.x * w0.y + xv.y * w1.y + xv.z * w2.y + xv.w * w3.y;
                acc[rr][2] += xv.x * w0.z + xv.y * w1.z + xv.z * w2.z + xv.w * w3.z;
                acc[rr][3] += xv.x * w0.w + xv.y * w1.w + xv.z * w2.w + xv.w * w3.w;
            }
        }
        float4 bv = *(const float4*)(b1 + tj * 4);
        #pragma unroll
        for (int rr = 0; rr < 2; ++rr) {
            float4 o;
            o.x = lrelu(acc[rr][0] + bv.x); o.y = lrelu(acc[rr][1] + bv.y);
            o.z = lrelu(acc[rr][2] + bv.z); o.w = lrelu(acc[rr][3] + bv.w);
            *(float4*)(&sH[tr * 2 + rr][tj * 4]) = o;
        }
    }
    __syncthreads();

    // layer 2: (32x128)@(128x256), cond-relu, store
    {
        const int tj = tid & 63, tr = tid >> 6;   // j0=tj*4, rows tr*4..tr*4+3
        float acc[4][4];
        #pragma unroll
        for (int a = 0; a < 4; ++a)
            #pragma unroll
            for (int b = 0; b < 4; ++b) acc[a][b] = 0.f;

        for (int k = 0; k < 128; k += 4) {
            float4 w0 = *(const float4*)(W2 + (size_t)(k + 0) * 256 + tj * 4);
            float4 w1 = *(const float4*)(W2 + (size_t)(k + 1) * 256 + tj * 4);
            float4 w2 = *(const float4*)(W2 + (size_t)(k + 2) * 256 + tj * 4);
            float4 w3 = *(const float4*)(W2 + (size_t)(k + 3) * 256 + tj * 4);
            #pragma unroll
            for (int rr = 0; rr < 4; ++rr) {
                float4 xv = *(const float4*)(&sH[tr * 4 + rr][k]);
                acc[rr][0] += xv.x * w0.x + xv.y * w1.x + xv.z * w2.x + xv.w * w3.x;
                acc[rr][1] += xv.x * w0.y + xv.y * w1.y + xv.z * w2.y + xv.w * w3.y;
                acc[rr][2] += xv.x * w0.z + xv.y * w1.z + xv.z * w2.z + xv.w * w3.z;
                acc[rr][3] += xv.x * w0.w + xv.y * w1.w + xv.z * w2.w + xv.w * w3.w;
            }
        }
        float4 bv = *(const float4*)(b2 + tj * 4);
        #pragma unroll
        for (int rr = 0; rr < 4; ++rr) {
            int gm = level * NM + row0 + tr * 4 + rr;
            bool po = (is_po[gm] == 1);
            float4 o;
            o.x = acc[rr][0] + bv.x; o.y = acc[rr][1] + bv.y;
            o.z = acc[rr][2] + bv.z; o.w = acc[rr][3] + bv.w;
            if (!po) {
                o.x = fmaxf(o.x, 0.f); o.y = fmaxf(o.y, 0.f);
                o.z = fmaxf(o.z, 0.f); o.w = fmaxf(o.w, 0.f);
            }
            *(float4*)(h_all + (size_t)gm * NH + tj * 4) = o;
        }
    }
}

// ---------- Final readout: 256 thr / 16 rows ----------
__global__ __launch_bounds__(256) void final_kernel(
    const float* __restrict__ h_gnn, const float* __restrict__ po_feat,
    const float* __restrict__ Wg1, const float* __restrict__ bg1,
    const float* __restrict__ Wg2, const float* __restrict__ bg2,
    const float* __restrict__ Wo1, const float* __restrict__ bo1,
    const float* __restrict__ Wo2, const float* __restrict__ bo2,
    float* __restrict__ out)
{
    const int tid = threadIdx.x;
    const int row0 = blockIdx.x * 16;
    __shared__ __align__(16) float sx[16][512];
    __shared__ __align__(16) float sg[16][128];
    __shared__ __align__(16) float so[16][NH];

    for (int x = tid; x < 16 * 64; x += 256) {
        int r = x >> 6, c = x & 63;
        *(float4*)(&sx[r][c * 4]) = *(const float4*)(h_gnn + (size_t)(row0 + r) * NH + c * 4);
    }
    for (int x = tid; x < 16 * 128; x += 256) {
        int r = x >> 7, j = x & 127;
        sg[r][j] = lrelu(po_feat[row0 + r] * Wg1[j] + bg1[j]);
    }
    __syncthreads();

    // h_global = sg @ Wg2 + bg2  -> sx[:, 256:]
    {
        const int tj = tid & 63, tr = tid >> 6;   // k0=tj*4, rows tr*4..tr*4+3
        float acc[4][4];
        #pragma unroll
        for (int a = 0; a < 4; ++a)
            #pragma unroll
            for (int b = 0; b < 4; ++b) acc[a][b] = 0.f;

        for (int k = 0; k < 128; k += 4) {
            float4 w0 = *(const float4*)(Wg2 + (size_t)(k + 0) * 256 + tj * 4);
            float4 w1 = *(const float4*)(Wg2 + (size_t)(k + 1) * 256 + tj * 4);
            float4 w2 = *(const float4*)(Wg2 + (size_t)(k + 2) * 256 + tj * 4);
            float4 w3 = *(const float4*)(Wg2 + (size_t)(k + 3) * 256 + tj * 4);
            #pragma unroll
            for (int rr = 0; rr < 4; ++rr) {
                float4 xv = *(const float4*)(&sg[tr * 4 + rr][k]);
                acc[rr][0] += xv.x * w0.x + xv.y * w1.x + xv.z * w2.x + xv.w * w3.x;
                acc[rr][1] += xv.x * w0.y + xv.y * w1.y + xv.z * w2.y + xv.w * w3.y;
                acc[rr][2] += xv.x * w0.z + xv.y * w1.z + xv.z * w2.z + xv.w * w3.z;
                acc[rr][3] += xv.x * w0.w + xv.y * w1.w + xv.z * w2.w + xv.w * w3.w;
            }
        }
        float4 bv = *(const float4*)(bg2 + tj * 4);
        #pragma unroll
        for (int rr = 0; rr < 4; ++rr) {
            float4 o;
            o.x = acc[rr][0] + bv.x; o.y = acc[rr][1] + bv.y;
            o.z = acc[rr][2] + bv.z; o.w = acc[rr][3] + bv.w;
            *(float4*)(&sx[tr * 4 + rr][256 + tj * 4]) = o;
        }
    }
    __syncthreads();

    // o1 = lrelu(sx @ Wo1 + bo1), K=512
    {
        const int tj = tid & 63, tr = tid >> 6;
        float acc[4][4];
        #pragma unroll
        for (int a = 0; a < 4; ++a)
            #pragma unroll
            for (int b = 0; b < 4; ++b) acc[a][b] = 0.f;

        for (int k = 0; k < 512; k += 4) {
            float4 w0 = *(const float4*)(Wo1 + (size_t)(k + 0) * 256 + tj * 4);
            float4 w1 = *(const float4*)(Wo1 + (size_t)(k + 1) * 256 + tj * 4);
            float4 w2 = *(const float4*)(Wo1 + (size_t)(k + 2) * 256 + tj * 4);
            float4 w3 = *(const float4*)(Wo1 + (size_t)(k + 3) * 256 + tj * 4);
            #pragma unroll
            for (int rr = 0; rr < 4; ++rr) {
                float4 xv = *(const float4*)(&sx[tr * 4 + rr][k]);
                acc[rr][0] += xv.x * w0.x + xv.y * w1.x + xv.z * w2.x + xv.w * w3.x;
                acc[rr][1] += xv.x * w0.y + xv.y * w1.y + xv.z * w2.y + xv.w * w3.y;
                acc[rr][2] += xv.x * w0.z + xv.y * w1.z + xv.z * w2.z + xv.w * w3.z;
                acc[rr][3] += xv.x * w0.w + xv.y * w1.w + xv.z * w2.w + xv.w * w3.w;
            }
        }
        float4 bv = *(const float4*)(bo1 + tj * 4);
        #pragma unroll
        for (int rr = 0; rr < 4; ++rr) {
            float4 o;
            o.x = lrelu(acc[rr][0] + bv.x); o.y = lrelu(acc[rr][1] + bv.y);
            o.z = lrelu(acc[rr][2] + bv.z); o.w = lrelu(acc[rr][3] + bv.w);
            *(float4*)(&so[tr * 4 + rr][tj * 4]) = o;
        }
    }
    __syncthreads();

    // out = so @ Wo2 + b
    {
        const int g = tid >> 4, l = tid & 15;
        float a = 0.f;
        for (int k = l; k < NH; k += 16) a += so[g][k] * Wo2[k];
        #pragma unroll
        for (int off = 1; off < 16; off <<= 1) a += __shfl_xor(a, off);
        if (l == 0) out[row0 + g] = a + bo2[0];
    }
}

extern "C" void kernel_launch(void* const* d_in, const int* in_sizes, int n_in,
                              void* d_out, int out_size, void* d_ws, size_t ws_size,
                              hipStream_t stream) {
    const float* W_pi1 = (const float*)d_in[0];
    const float* b_pi1 = (const float*)d_in[1];
    const float* W_pi2 = (const float*)d_in[2];
    const float* b_pi2 = (const float*)d_in[3];
    const float* W_t1  = (const float*)d_in[4];
    const float* b_t1  = (const float*)d_in[5];
    const float* W_t2  = (const float*)d_in[6];
    const float* b_t2  = (const float*)d_in[7];
    const float* W_p1  = (const float*)d_in[8];
    const float* b_p1  = (const float*)d_in[9];
    const float* W_p2  = (const float*)d_in[10];
    const float* b_p2  = (const float*)d_in[11];
    const float* W_n1  = (const float*)d_in[12];
    const float* b_n1  = (const float*)d_in[13];
    const float* W_n2  = (const float*)d_in[14];
    const float* b_n2  = (const float*)d_in[15];
    const float* W_g1  = (const float*)d_in[16];
    const float* b_g1  = (const float*)d_in[17];
    const float* W_g2  = (const float*)d_in[18];
    const float* b_g2  = (const float*)d_in[19];
    const float* W_o1  = (const float*)d_in[20];
    const float* b_o1  = (const float*)d_in[21];
    const float* W_o2  = (const float*)d_in[22];
    const float* b_o2  = (const float*)d_in[23];
    const float* av    = (const float*)d_in[24];
    const float* feat  = (const float*)d_in[25];
    const float* delay = (const float*)d_in[26];
    const float* bit_pos = (const float*)d_in[27];
    const float* po_feat = (const float*)d_in[28];
    const int*   is_po   = (const int*)d_in[29];
    const int*   nbr_idx = (const int*)d_in[30];

    float* h_all = (float*)d_ws;                       // NN*256 floats
    float* neigh = h_all + (size_t)NN * NH;            // NM*256 floats
    float* cst   = neigh + (size_t)NM * NH;            // 128 floats
    float* out   = (float*)d_out;

    precomp_kernel<<<1, 64, 0, stream>>>(W_t2, b_t2, W_p2, b_p2, av, cst);

    level0_kernel<<<NM / 32, 512, 0, stream>>>(delay, W_pi1, b_pi1, W_pi2, b_pi2, h_all);

    for (int level = 1; level < NL; ++level) {
        attn_kernel<<<(NM * 64) / 256, 256, 0, stream>>>(h_all, feat, bit_pos, nbr_idx,
                                                         W_t1, b_t1, W_p1, b_p1,
                                                         av, cst, neigh, level);
        mlp_n_kernel<<<NM / 32, 512, 0, stream>>>(neigh, W_n1, b_n1, W_n2, b_n2,
                                                  is_po, h_all, level);
    }

    final_kernel<<<NM / 16, 256, 0, stream>>>(h_all + (size_t)(NN - NM) * NH, po_feat,
                                              W_g1, b_g1, W_g2, b_g2,
                                              W_o1, b_o1, W_o2, b_o2, out);
}